// Round 5
// baseline (801.379 us; speedup 1.0000x reference)
//
#include <hip/hip_runtime.h>

// LightGCN 3-hop propagation on MI355X.
// R5: k_agg rewritten with wave-uniform scalar edge loads (s_load_dwordx8
// batches, weight as SGPR operand to v_fmac) -- removes 12.8M ds_bpermute
// broadcasts per dispatch. bf16 gather tables (R4), radix-partition CSR
// build (R3) unchanged.

#define NU     100000
#define NE     100000
#define DD     64
#define NNZ    3200000
#define NROWS  200000            // NE entity rows then NU user rows
#define EMB    6400000           // 100000 * 64
#define TOT    6400000           // 2*NNZ records

#define SHIFT  9                 // rows per bucket = 512
#define RPB    512
#define NBUK   391               // ceil(NROWS / RPB)
#define NBLK   512               // partition tiles
#define TILE   (NNZ / NBLK)      // 6250 edges per tile (exact)

__device__ __forceinline__ float bf2f(ushort v) {
    return __uint_as_float(((unsigned int)v) << 16);
}
__device__ __forceinline__ ushort f2bf(float x) {
    unsigned int b = __float_as_uint(x);
    return (ushort)((b + 0x7FFF + ((b >> 16) & 1)) >> 16);   // RNE
}

// ---------------------------------------------------------------- init
__global__ void k_init(const float4* __restrict__ uemb,
                       const float4* __restrict__ eemb,
                       ushort4* __restrict__ ucur, ushort4* __restrict__ ecur,
                       float4* __restrict__ out) {
    const int n4 = EMB / 4;
    int tid = blockIdx.x * blockDim.x + threadIdx.x;
    int stride = gridDim.x * blockDim.x;
    for (int i = tid; i < n4; i += stride) {
        float4 u = uemb[i], e = eemb[i];
        ushort4 ub, eb;
        ub.x = f2bf(u.x); ub.y = f2bf(u.y); ub.z = f2bf(u.z); ub.w = f2bf(u.w);
        eb.x = f2bf(e.x); eb.y = f2bf(e.y); eb.z = f2bf(e.z); eb.w = f2bf(e.w);
        ucur[i] = ub;
        ecur[i] = eb;
        out[i]      = e;      // entity_res init = entity_emb
        out[n4 + i] = u;      // user_res init = user_emb
    }
}

// ---------------------------------------------------------------- per-(block,bucket) histogram
__global__ void __launch_bounds__(256) k_bhist(const int* __restrict__ eu,
                                               const int* __restrict__ ee,
                                               int* __restrict__ pos) {
    __shared__ int h[NBUK];
    int t = threadIdx.x;
    for (int b = t; b < NBUK; b += 256) h[b] = 0;
    __syncthreads();
    int start = blockIdx.x * TILE, end = start + TILE;
    for (int i = start + t; i < end; i += 256) {
        atomicAdd(&h[ee[i] >> SHIFT], 1);
        atomicAdd(&h[(NE + eu[i]) >> SHIFT], 1);
    }
    __syncthreads();
    for (int b = t; b < NBUK; b += 256) pos[b * NBLK + blockIdx.x] = h[b];
}

// ---------------------------------------------------------------- generic 3-kernel exclusive scan
__global__ void k_gsum(const int* __restrict__ a, int* __restrict__ partials, int n) {
    int gid = blockIdx.x * 256 + threadIdx.x;
    int v = (gid < n) ? a[gid] : 0;
    for (int d = 32; d; d >>= 1) v += __shfl_down(v, d);
    __shared__ int ws[4];
    if ((threadIdx.x & 63) == 0) ws[threadIdx.x >> 6] = v;
    __syncthreads();
    if (threadIdx.x == 0) partials[blockIdx.x] = ws[0] + ws[1] + ws[2] + ws[3];
}

__global__ void k_gtop(int* __restrict__ partials, int nb) {
    int tid = threadIdx.x;
    int v = (tid < nb) ? partials[tid] : 0;
    int lane = tid & 63, wid = tid >> 6;
    int x = v;
    for (int d = 1; d < 64; d <<= 1) { int tv = __shfl_up(x, d); if (lane >= d) x += tv; }
    __shared__ int wsum[16], woff[16];
    if (lane == 63) wsum[wid] = x;
    __syncthreads();
    if (tid < 16) {
        int s = 0;
        for (int i = 0; i < tid; i++) s += wsum[i];
        woff[tid] = s;
    }
    __syncthreads();
    int excl = x + woff[wid] - v;
    if (tid < nb) partials[tid] = excl;
}

__global__ void k_gfinal(int* __restrict__ a, const int* __restrict__ partials, int n) {
    int gid = blockIdx.x * 256 + threadIdx.x;
    int v = (gid < n) ? a[gid] : 0;
    int lane = threadIdx.x & 63, wid = threadIdx.x >> 6;
    int x = v;
    for (int d = 1; d < 64; d <<= 1) { int tv = __shfl_up(x, d); if (lane >= d) x += tv; }
    __shared__ int ws[4];
    if (lane == 63) ws[wid] = x;
    __syncthreads();
    int add = 0;
    for (int i = 0; i < wid; i++) add += ws[i];
    int excl = x - v + add + partials[blockIdx.x];
    if (gid < n) a[gid] = excl;
}

// ---------------------------------------------------------------- partition pass B
// rec.x = (row_in_bucket << 17) | src_col   (col < 2^17, rib < 512)
__global__ void __launch_bounds__(256) k_partB(const int* __restrict__ eu,
                                               const int* __restrict__ ee,
                                               const float* __restrict__ ew,
                                               const int* __restrict__ pos,
                                               int2* __restrict__ recs) {
    __shared__ int cur[NBUK];
    int t = threadIdx.x;
    for (int b = t; b < NBUK; b += 256) cur[b] = pos[b * NBLK + blockIdx.x];
    __syncthreads();
    int start = blockIdx.x * TILE, end = start + TILE;
    for (int i = start + t; i < end; i += 256) {
        int u = eu[i], e = ee[i];
        int wb = __float_as_int(ew[i]);
        int r1 = e;                         // entity-dest row, src = user u
        int p1 = atomicAdd(&cur[r1 >> SHIFT], 1);
        recs[p1] = make_int2(((r1 & (RPB - 1)) << 17) | u, wb);
        int r2 = NE + u;                    // user-dest row, src = entity e
        int p2 = atomicAdd(&cur[r2 >> SHIFT], 1);
        recs[p2] = make_int2(((r2 & (RPB - 1)) << 17) | e, wb);
    }
}

// ---------------------------------------------------------------- partition pass C
__global__ void __launch_bounds__(256) k_partC(const int* __restrict__ pos,
                                               const int2* __restrict__ recs,
                                               int2* __restrict__ edges,
                                               int* __restrict__ row_ptr) {
    int b = blockIdx.x;
    int t = threadIdx.x;
    __shared__ int hist[RPB];
    __shared__ int curs[RPB];
    __shared__ int wtot[4];
    int base = pos[b * NBLK];
    int nend = (b == NBUK - 1) ? TOT : pos[(b + 1) * NBLK];
    for (int r = t; r < RPB; r += 256) hist[r] = 0;
    __syncthreads();
    for (int i = base + t; i < nend; i += 256)
        atomicAdd(&hist[recs[i].x >> 17], 1);
    __syncthreads();
    int h0 = hist[2 * t], h1 = hist[2 * t + 1];
    int s = h0 + h1;
    int lane = t & 63, wid = t >> 6;
    int x = s;
    for (int d = 1; d < 64; d <<= 1) { int v = __shfl_up(x, d); if (lane >= d) x += v; }
    if (lane == 63) wtot[wid] = x;
    __syncthreads();
    int woff = 0;
    for (int i = 0; i < wid; i++) woff += wtot[i];
    int e0 = base + woff + x - s;          // absolute exclusive pos of row 2t
    curs[2 * t]     = e0;
    curs[2 * t + 1] = e0 + h0;
    int row0 = (b << SHIFT) + 2 * t;
    if (row0 < NROWS)     row_ptr[row0]     = e0;
    if (row0 + 1 < NROWS) row_ptr[row0 + 1] = e0 + h0;
    if (b == 0 && t == 0) row_ptr[NROWS]    = TOT;
    __syncthreads();
    for (int i = base + t; i < nend; i += 256) {
        int2 rc = recs[i];
        int p = atomicAdd(&curs[rc.x >> 17], 1);
        edges[p] = make_int2(rc.x & 0x1FFFF, rc.y);
    }
}

// ---------------------------------------------------------------- aggregation
// One wave per destination row; lane = feature index (D=64).
// Edge records are wave-uniform -> scalar s_load path (no shuffles, no
// predication); weight rides as SGPR operand into v_fmac.
__global__ void __launch_bounds__(256) k_agg(
        const int* __restrict__ row_ptr, const int2* __restrict__ edges,
        const ushort* __restrict__ uold, const ushort* __restrict__ eold,
        ushort* __restrict__ unew, ushort* __restrict__ enew,
        float* __restrict__ out) {
    int wid = threadIdx.x >> 6;
    int row = __builtin_amdgcn_readfirstlane(blockIdx.x * 4 + wid);
    if (row >= NROWS) return;
    int lane = threadIdx.x & 63;

    const ushort* __restrict__ src;
    ushort* dst; float* op;
    if (row < NE) {                      // entity destination: gather user rows
        src = uold;
        dst = enew + (size_t)row * DD;
        op  = out  + (size_t)row * DD;
    } else {                             // user destination: gather entity rows
        int r = row - NE;
        src = eold;
        dst = unew + (size_t)r * DD;
        op  = out + EMB + (size_t)r * DD;
    }

    int s = row_ptr[row], e = row_ptr[row + 1];
    float acc = 0.f;
    int j = s;
    for (; j + 4 <= e; j += 4) {
        int2 c0 = edges[j];
        int2 c1 = edges[j + 1];
        int2 c2 = edges[j + 2];
        int2 c3 = edges[j + 3];
        float g0 = bf2f(src[c0.x * DD + lane]);
        float g1 = bf2f(src[c1.x * DD + lane]);
        float g2 = bf2f(src[c2.x * DD + lane]);
        float g3 = bf2f(src[c3.x * DD + lane]);
        acc = fmaf(__int_as_float(c0.y), g0, acc);
        acc = fmaf(__int_as_float(c1.y), g1, acc);
        acc = fmaf(__int_as_float(c2.y), g2, acc);
        acc = fmaf(__int_as_float(c3.y), g3, acc);
    }
    for (; j < e; j++) {
        int2 c = edges[j];
        acc = fmaf(__int_as_float(c.y), bf2f(src[c.x * DD + lane]), acc);
    }

    float sq = acc * acc;
    for (int d = 32; d; d >>= 1) sq += __shfl_xor(sq, d);
    float nv = acc / fmaxf(sqrtf(sq), 1e-12f);

    dst[lane] = f2bf(nv);   // next-hop embedding (bf16)
    op[lane] += nv;         // residual accumulate into d_out (f32)
}

// ---------------------------------------------------------------- launch
extern "C" void kernel_launch(void* const* d_in, const int* in_sizes, int n_in,
                              void* d_out, int out_size, void* d_ws, size_t ws_size,
                              hipStream_t stream) {
    const float* uemb = (const float*)d_in[0];
    const float* eemb = (const float*)d_in[1];
    const int*   eu   = (const int*)d_in[2];
    const int*   ee   = (const int*)d_in[3];
    const float* ew   = (const float*)d_in[4];
    float* out = (float*)d_out;

    // workspace carve-up (~156 MB)
    char* ws = (char*)d_ws;
    size_t off = 0;
    ushort* ucur0 = (ushort*)(ws + off); off += (size_t)EMB * 2;   // 12.8 MB each
    ushort* ecur0 = (ushort*)(ws + off); off += (size_t)EMB * 2;
    ushort* ucur1 = (ushort*)(ws + off); off += (size_t)EMB * 2;
    ushort* ecur1 = (ushort*)(ws + off); off += (size_t)EMB * 2;
    int2*  recs    = (int2*)(ws + off);  off += (size_t)TOT * 8;   // 51.2 MB
    int2*  edges   = (int2*)(ws + off);  off += (size_t)TOT * 8;   // 51.2 MB
    int*   row_ptr = (int*)(ws + off);   off += (size_t)(NROWS + 1) * 4;
    int*   pos     = (int*)(ws + off);   off += (size_t)NBUK * NBLK * 4;
    int*   partials= (int*)(ws + off);   off += 1024 * 4;

    // 1. convert embeddings to bf16 tables, init output residuals
    k_init<<<2048, 256, 0, stream>>>((const float4*)uemb, (const float4*)eemb,
                                     (ushort4*)ucur0, (ushort4*)ecur0, (float4*)out);

    // 2. per-(block,bucket) histogram
    k_bhist<<<NBLK, 256, 0, stream>>>(eu, ee, pos);

    // 3. exclusive scan of NBUK*NBLK counters (bucket-major)
    const int NSCAN = NBUK * NBLK;               // 200192
    const int NB = (NSCAN + 255) / 256;          // 782
    k_gsum<<<NB, 256, 0, stream>>>(pos, partials, NSCAN);
    k_gtop<<<1, 1024, 0, stream>>>(partials, NB);
    k_gfinal<<<NB, 256, 0, stream>>>(pos, partials, NSCAN);

    // 4. partition into bucket-major staging (coalesced block-owned runs)
    k_partB<<<NBLK, 256, 0, stream>>>(eu, ee, ew, pos, recs);

    // 5. per-bucket scatter to final CSR order + emit row_ptr
    k_partC<<<NBUK, 256, 0, stream>>>(pos, recs, edges, row_ptr);

    // 6. three fused aggregation hops
    const int AB = (NROWS + 3) / 4;      // 50000 blocks, 4 waves = 4 rows each
    k_agg<<<AB, 256, 0, stream>>>(row_ptr, edges, ucur0, ecur0, ucur1, ecur1, out);
    k_agg<<<AB, 256, 0, stream>>>(row_ptr, edges, ucur1, ecur1, ucur0, ecur0, out);
    k_agg<<<AB, 256, 0, stream>>>(row_ptr, edges, ucur0, ecur0, ucur1, ecur1, out);
}

// Round 7
// 720.990 us; speedup vs baseline: 1.1115x; 1.1115x over previous
//
#include <hip/hip_runtime.h>

// LightGCN 3-hop propagation on MI355X.
// R6/R7: k_agg pair-gather layout -- each lane loads a uint (2 bf16 feats),
// 32 lanes per row, wave halves process even/odd edge of a pair => half the
// VMEM instructions, 2x bytes in flight per wave (R5 was gather-MLP-bound).
// Edge records stay wave-uniform scalar loads; half-select is v_cndmask.
// bf16 gather tables (R4), radix-partition CSR build (R3) unchanged.

#define NU     100000
#define NE     100000
#define DD     64
#define NNZ    3200000
#define NROWS  200000            // NE entity rows then NU user rows
#define EMB    6400000           // 100000 * 64
#define TOT    6400000           // 2*NNZ records

#define SHIFT  9                 // rows per bucket = 512
#define RPB    512
#define NBUK   391               // ceil(NROWS / RPB)
#define NBLK   512               // partition tiles
#define TILE   (NNZ / NBLK)      // 6250 edges per tile (exact)

__device__ __forceinline__ float bf2f(ushort v) {
    return __uint_as_float(((unsigned int)v) << 16);
}
__device__ __forceinline__ ushort f2bf(float x) {
    unsigned int b = __float_as_uint(x);
    return (ushort)((b + 0x7FFF + ((b >> 16) & 1)) >> 16);   // RNE
}

// ---------------------------------------------------------------- init
__global__ void k_init(const float4* __restrict__ uemb,
                       const float4* __restrict__ eemb,
                       ushort4* __restrict__ ucur, ushort4* __restrict__ ecur,
                       float4* __restrict__ out) {
    const int n4 = EMB / 4;
    int tid = blockIdx.x * blockDim.x + threadIdx.x;
    int stride = gridDim.x * blockDim.x;
    for (int i = tid; i < n4; i += stride) {
        float4 u = uemb[i], e = eemb[i];
        ushort4 ub, eb;
        ub.x = f2bf(u.x); ub.y = f2bf(u.y); ub.z = f2bf(u.z); ub.w = f2bf(u.w);
        eb.x = f2bf(e.x); eb.y = f2bf(e.y); eb.z = f2bf(e.z); eb.w = f2bf(e.w);
        ucur[i] = ub;
        ecur[i] = eb;
        out[i]      = e;      // entity_res init = entity_emb
        out[n4 + i] = u;      // user_res init = user_emb
    }
}

// ---------------------------------------------------------------- per-(block,bucket) histogram
__global__ void __launch_bounds__(256) k_bhist(const int* __restrict__ eu,
                                               const int* __restrict__ ee,
                                               int* __restrict__ pos) {
    __shared__ int h[NBUK];
    int t = threadIdx.x;
    for (int b = t; b < NBUK; b += 256) h[b] = 0;
    __syncthreads();
    int start = blockIdx.x * TILE, end = start + TILE;
    for (int i = start + t; i < end; i += 256) {
        atomicAdd(&h[ee[i] >> SHIFT], 1);
        atomicAdd(&h[(NE + eu[i]) >> SHIFT], 1);
    }
    __syncthreads();
    for (int b = t; b < NBUK; b += 256) pos[b * NBLK + blockIdx.x] = h[b];
}

// ---------------------------------------------------------------- generic 3-kernel exclusive scan
__global__ void k_gsum(const int* __restrict__ a, int* __restrict__ partials, int n) {
    int gid = blockIdx.x * 256 + threadIdx.x;
    int v = (gid < n) ? a[gid] : 0;
    for (int d = 32; d; d >>= 1) v += __shfl_down(v, d);
    __shared__ int ws[4];
    if ((threadIdx.x & 63) == 0) ws[threadIdx.x >> 6] = v;
    __syncthreads();
    if (threadIdx.x == 0) partials[blockIdx.x] = ws[0] + ws[1] + ws[2] + ws[3];
}

__global__ void k_gtop(int* __restrict__ partials, int nb) {
    int tid = threadIdx.x;
    int v = (tid < nb) ? partials[tid] : 0;
    int lane = tid & 63, wid = tid >> 6;
    int x = v;
    for (int d = 1; d < 64; d <<= 1) { int tv = __shfl_up(x, d); if (lane >= d) x += tv; }
    __shared__ int wsum[16], woff[16];
    if (lane == 63) wsum[wid] = x;
    __syncthreads();
    if (tid < 16) {
        int s = 0;
        for (int i = 0; i < tid; i++) s += wsum[i];
        woff[tid] = s;
    }
    __syncthreads();
    int excl = x + woff[wid] - v;
    if (tid < nb) partials[tid] = excl;
}

__global__ void k_gfinal(int* __restrict__ a, const int* __restrict__ partials, int n) {
    int gid = blockIdx.x * 256 + threadIdx.x;
    int v = (gid < n) ? a[gid] : 0;
    int lane = threadIdx.x & 63, wid = threadIdx.x >> 6;
    int x = v;
    for (int d = 1; d < 64; d <<= 1) { int tv = __shfl_up(x, d); if (lane >= d) x += tv; }
    __shared__ int ws[4];
    if (lane == 63) ws[wid] = x;
    __syncthreads();
    int add = 0;
    for (int i = 0; i < wid; i++) add += ws[i];
    int excl = x - v + add + partials[blockIdx.x];
    if (gid < n) a[gid] = excl;
}

// ---------------------------------------------------------------- partition pass B
// rec.x = (row_in_bucket << 17) | src_col   (col < 2^17, rib < 512)
__global__ void __launch_bounds__(256) k_partB(const int* __restrict__ eu,
                                               const int* __restrict__ ee,
                                               const float* __restrict__ ew,
                                               const int* __restrict__ pos,
                                               int2* __restrict__ recs) {
    __shared__ int cur[NBUK];
    int t = threadIdx.x;
    for (int b = t; b < NBUK; b += 256) cur[b] = pos[b * NBLK + blockIdx.x];
    __syncthreads();
    int start = blockIdx.x * TILE, end = start + TILE;
    for (int i = start + t; i < end; i += 256) {
        int u = eu[i], e = ee[i];
        int wb = __float_as_int(ew[i]);
        int r1 = e;                         // entity-dest row, src = user u
        int p1 = atomicAdd(&cur[r1 >> SHIFT], 1);
        recs[p1] = make_int2(((r1 & (RPB - 1)) << 17) | u, wb);
        int r2 = NE + u;                    // user-dest row, src = entity e
        int p2 = atomicAdd(&cur[r2 >> SHIFT], 1);
        recs[p2] = make_int2(((r2 & (RPB - 1)) << 17) | e, wb);
    }
}

// ---------------------------------------------------------------- partition pass C
__global__ void __launch_bounds__(256) k_partC(const int* __restrict__ pos,
                                               const int2* __restrict__ recs,
                                               int2* __restrict__ edges,
                                               int* __restrict__ row_ptr) {
    int b = blockIdx.x;
    int t = threadIdx.x;
    __shared__ int hist[RPB];
    __shared__ int curs[RPB];
    __shared__ int wtot[4];
    int base = pos[b * NBLK];
    int nend = (b == NBUK - 1) ? TOT : pos[(b + 1) * NBLK];
    for (int r = t; r < RPB; r += 256) hist[r] = 0;
    __syncthreads();
    for (int i = base + t; i < nend; i += 256)
        atomicAdd(&hist[recs[i].x >> 17], 1);
    __syncthreads();
    int h0 = hist[2 * t], h1 = hist[2 * t + 1];
    int s = h0 + h1;
    int lane = t & 63, wid = t >> 6;
    int x = s;
    for (int d = 1; d < 64; d <<= 1) { int v = __shfl_up(x, d); if (lane >= d) x += v; }
    if (lane == 63) wtot[wid] = x;
    __syncthreads();
    int woff = 0;
    for (int i = 0; i < wid; i++) woff += wtot[i];
    int e0 = base + woff + x - s;          // absolute exclusive pos of row 2t
    curs[2 * t]     = e0;
    curs[2 * t + 1] = e0 + h0;
    int row0 = (b << SHIFT) + 2 * t;
    if (row0 < NROWS)     row_ptr[row0]     = e0;
    if (row0 + 1 < NROWS) row_ptr[row0 + 1] = e0 + h0;
    if (b == 0 && t == 0) row_ptr[NROWS]    = TOT;
    __syncthreads();
    for (int i = base + t; i < nend; i += 256) {
        int2 rc = recs[i];
        int p = atomicAdd(&curs[rc.x >> 17], 1);
        edges[p] = make_int2(rc.x & 0x1FFFF, rc.y);
    }
}

// ---------------------------------------------------------------- aggregation
// One wave per destination row. Lane layout: l31 = lane&31 selects the
// feature pair (uint = 2 bf16); h = lane>>5 selects even/odd edge of a pair.
// Edge records are wave-uniform scalar loads; half-select via cndmask.
__global__ void __launch_bounds__(256) k_agg(
        const int* __restrict__ row_ptr, const int2* __restrict__ edges,
        const ushort* __restrict__ uold, const ushort* __restrict__ eold,
        ushort* __restrict__ unew, ushort* __restrict__ enew,
        float* __restrict__ out) {
    int wid = threadIdx.x >> 6;
    int row = __builtin_amdgcn_readfirstlane(blockIdx.x * 4 + wid);
    if (row >= NROWS) return;
    int lane = threadIdx.x & 63;
    int h = lane >> 5;           // 0: even edge of pair, 1: odd edge
    int l31 = lane & 31;         // feature-pair index (feats 2*l31, 2*l31+1)

    const uint* __restrict__ src;    // row stride = 32 uints (64 bf16)
    ushort* dst; float* op;
    if (row < NE) {                      // entity destination: gather user rows
        src = (const uint*)uold;
        dst = enew + (size_t)row * DD;
        op  = out  + (size_t)row * DD;
    } else {                             // user destination: gather entity rows
        int r = row - NE;
        src = (const uint*)eold;
        dst = unew + (size_t)r * DD;
        op  = out + EMB + (size_t)r * DD;
    }

    int s = row_ptr[row], e = row_ptr[row + 1];
    float ax = 0.f, ay = 0.f;

    int j = s;
    for (; j + 8 <= e; j += 8) {
        int2 E0 = edges[j+0], E1 = edges[j+1], E2 = edges[j+2], E3 = edges[j+3];
        int2 E4 = edges[j+4], E5 = edges[j+5], E6 = edges[j+6], E7 = edges[j+7];
        int   c0 = h ? E1.x : E0.x;
        int   c1 = h ? E3.x : E2.x;
        int   c2 = h ? E5.x : E4.x;
        int   c3 = h ? E7.x : E6.x;
        float w0 = __int_as_float(h ? E1.y : E0.y);
        float w1 = __int_as_float(h ? E3.y : E2.y);
        float w2 = __int_as_float(h ? E5.y : E4.y);
        float w3 = __int_as_float(h ? E7.y : E6.y);
        uint g0 = src[c0 * 32 + l31];
        uint g1 = src[c1 * 32 + l31];
        uint g2 = src[c2 * 32 + l31];
        uint g3 = src[c3 * 32 + l31];
        ax = fmaf(w0, __uint_as_float(g0 << 16), ax);
        ay = fmaf(w0, __uint_as_float(g0 & 0xFFFF0000u), ay);
        ax = fmaf(w1, __uint_as_float(g1 << 16), ax);
        ay = fmaf(w1, __uint_as_float(g1 & 0xFFFF0000u), ay);
        ax = fmaf(w2, __uint_as_float(g2 << 16), ax);
        ay = fmaf(w2, __uint_as_float(g2 & 0xFFFF0000u), ay);
        ax = fmaf(w3, __uint_as_float(g3 << 16), ax);
        ay = fmaf(w3, __uint_as_float(g3 & 0xFFFF0000u), ay);
    }
    for (; j + 2 <= e; j += 2) {
        int2 A = edges[j], B = edges[j+1];
        int   c = h ? B.x : A.x;
        float w = __int_as_float(h ? B.y : A.y);
        uint g = src[c * 32 + l31];
        ax = fmaf(w, __uint_as_float(g << 16), ax);
        ay = fmaf(w, __uint_as_float(g & 0xFFFF0000u), ay);
    }
    if (j < e) {                      // odd tail: half 1 contributes zero
        int2 A = edges[j];
        int   c = h ? 0 : A.x;
        float w = __int_as_float(h ? 0 : A.y);
        uint g = src[c * 32 + l31];
        ax = fmaf(w, __uint_as_float(g << 16), ax);
        ay = fmaf(w, __uint_as_float(g & 0xFFFF0000u), ay);
    }

    // combine even/odd halves (lane l and l+32 hold same feature pair)
    ax += __shfl_xor(ax, 32);
    ay += __shfl_xor(ay, 32);

    // sum of squares across the 32 feature-pairs of this half
    float sq = fmaf(ax, ax, ay * ay);
    for (int d = 16; d; d >>= 1) sq += __shfl_xor(sq, d);
    float nrm = fmaxf(sqrtf(sq), 1e-12f);
    float nx = ax / nrm, ny = ay / nrm;

    if (lane < 32) {          // half 0: write bf16 next-hop row (packed)
        uint p = (uint)f2bf(nx) | ((uint)f2bf(ny) << 16);
        ((uint*)dst)[l31] = p;
    } else {                  // half 1: f32 residual accumulate into d_out
        float2* o2 = (float2*)op;
        float2 c = o2[l31];
        c.x += nx; c.y += ny;
        o2[l31] = c;
    }
}

// ---------------------------------------------------------------- launch
extern "C" void kernel_launch(void* const* d_in, const int* in_sizes, int n_in,
                              void* d_out, int out_size, void* d_ws, size_t ws_size,
                              hipStream_t stream) {
    const float* uemb = (const float*)d_in[0];
    const float* eemb = (const float*)d_in[1];
    const int*   eu   = (const int*)d_in[2];
    const int*   ee   = (const int*)d_in[3];
    const float* ew   = (const float*)d_in[4];
    float* out = (float*)d_out;

    // workspace carve-up (~156 MB)
    char* ws = (char*)d_ws;
    size_t off = 0;
    ushort* ucur0 = (ushort*)(ws + off); off += (size_t)EMB * 2;   // 12.8 MB each
    ushort* ecur0 = (ushort*)(ws + off); off += (size_t)EMB * 2;
    ushort* ucur1 = (ushort*)(ws + off); off += (size_t)EMB * 2;
    ushort* ecur1 = (ushort*)(ws + off); off += (size_t)EMB * 2;
    int2*  recs    = (int2*)(ws + off);  off += (size_t)TOT * 8;   // 51.2 MB
    int2*  edges   = (int2*)(ws + off);  off += (size_t)TOT * 8;   // 51.2 MB
    int*   row_ptr = (int*)(ws + off);   off += (size_t)(NROWS + 1) * 4;
    int*   pos     = (int*)(ws + off);   off += (size_t)NBUK * NBLK * 4;
    int*   partials= (int*)(ws + off);   off += 1024 * 4;

    // 1. convert embeddings to bf16 tables, init output residuals
    k_init<<<2048, 256, 0, stream>>>((const float4*)uemb, (const float4*)eemb,
                                     (ushort4*)ucur0, (ushort4*)ecur0, (float4*)out);

    // 2. per-(block,bucket) histogram
    k_bhist<<<NBLK, 256, 0, stream>>>(eu, ee, pos);

    // 3. exclusive scan of NBUK*NBLK counters (bucket-major)
    const int NSCAN = NBUK * NBLK;               // 200192
    const int NB = (NSCAN + 255) / 256;          // 782
    k_gsum<<<NB, 256, 0, stream>>>(pos, partials, NSCAN);
    k_gtop<<<1, 1024, 0, stream>>>(partials, NB);
    k_gfinal<<<NB, 256, 0, stream>>>(pos, partials, NSCAN);

    // 4. partition into bucket-major staging (coalesced block-owned runs)
    k_partB<<<NBLK, 256, 0, stream>>>(eu, ee, ew, pos, recs);

    // 5. per-bucket scatter to final CSR order + emit row_ptr
    k_partC<<<NBUK, 256, 0, stream>>>(pos, recs, edges, row_ptr);

    // 6. three fused aggregation hops
    const int AB = (NROWS + 3) / 4;      // 50000 blocks, 4 waves = 4 rows each
    k_agg<<<AB, 256, 0, stream>>>(row_ptr, edges, ucur0, ecur0, ucur1, ecur1, out);
    k_agg<<<AB, 256, 0, stream>>>(row_ptr, edges, ucur1, ecur1, ucur0, ecur0, out);
    k_agg<<<AB, 256, 0, stream>>>(row_ptr, edges, ucur0, ecur0, ucur1, ecur1, out);
}

// Round 8
// 720.908 us; speedup vs baseline: 1.1116x; 1.0001x over previous
//
#include <hip/hip_runtime.h>

// LightGCN 3-hop propagation on MI355X.
// R8: k_agg quad-gather -- lane = (slot = edge-of-quad, l15 = feature quad,
// uint2 = 4 bf16). Edge records via per-lane broadcast VMEM load of one
// contiguous 32B quad (no cndmask selection, no SMEM path); gather fetches
// 4 rows per instruction; f32x2 packed accumulate (v_pk_fma candidates).
// bf16 gather tables (R4), radix-partition CSR build (R3) unchanged.

#define NU     100000
#define NE     100000
#define DD     64
#define NNZ    3200000
#define NROWS  200000            // NE entity rows then NU user rows
#define EMB    6400000           // 100000 * 64
#define TOT    6400000           // 2*NNZ records

#define SHIFT  9                 // rows per bucket = 512
#define RPB    512
#define NBUK   391               // ceil(NROWS / RPB)
#define NBLK   512               // partition tiles
#define TILE   (NNZ / NBLK)      // 6250 edges per tile (exact)

typedef float f32x2 __attribute__((ext_vector_type(2)));

__device__ __forceinline__ float bf2f(ushort v) {
    return __uint_as_float(((unsigned int)v) << 16);
}
__device__ __forceinline__ ushort f2bf(float x) {
    unsigned int b = __float_as_uint(x);
    return (ushort)((b + 0x7FFF + ((b >> 16) & 1)) >> 16);   // RNE
}

// ---------------------------------------------------------------- init
__global__ void k_init(const float4* __restrict__ uemb,
                       const float4* __restrict__ eemb,
                       ushort4* __restrict__ ucur, ushort4* __restrict__ ecur,
                       float4* __restrict__ out) {
    const int n4 = EMB / 4;
    int tid = blockIdx.x * blockDim.x + threadIdx.x;
    int stride = gridDim.x * blockDim.x;
    for (int i = tid; i < n4; i += stride) {
        float4 u = uemb[i], e = eemb[i];
        ushort4 ub, eb;
        ub.x = f2bf(u.x); ub.y = f2bf(u.y); ub.z = f2bf(u.z); ub.w = f2bf(u.w);
        eb.x = f2bf(e.x); eb.y = f2bf(e.y); eb.z = f2bf(e.z); eb.w = f2bf(e.w);
        ucur[i] = ub;
        ecur[i] = eb;
        out[i]      = e;      // entity_res init = entity_emb
        out[n4 + i] = u;      // user_res init = user_emb
    }
}

// ---------------------------------------------------------------- per-(block,bucket) histogram
__global__ void __launch_bounds__(256) k_bhist(const int* __restrict__ eu,
                                               const int* __restrict__ ee,
                                               int* __restrict__ pos) {
    __shared__ int h[NBUK];
    int t = threadIdx.x;
    for (int b = t; b < NBUK; b += 256) h[b] = 0;
    __syncthreads();
    int start = blockIdx.x * TILE, end = start + TILE;
    for (int i = start + t; i < end; i += 256) {
        atomicAdd(&h[ee[i] >> SHIFT], 1);
        atomicAdd(&h[(NE + eu[i]) >> SHIFT], 1);
    }
    __syncthreads();
    for (int b = t; b < NBUK; b += 256) pos[b * NBLK + blockIdx.x] = h[b];
}

// ---------------------------------------------------------------- generic 3-kernel exclusive scan
__global__ void k_gsum(const int* __restrict__ a, int* __restrict__ partials, int n) {
    int gid = blockIdx.x * 256 + threadIdx.x;
    int v = (gid < n) ? a[gid] : 0;
    for (int d = 32; d; d >>= 1) v += __shfl_down(v, d);
    __shared__ int ws[4];
    if ((threadIdx.x & 63) == 0) ws[threadIdx.x >> 6] = v;
    __syncthreads();
    if (threadIdx.x == 0) partials[blockIdx.x] = ws[0] + ws[1] + ws[2] + ws[3];
}

__global__ void k_gtop(int* __restrict__ partials, int nb) {
    int tid = threadIdx.x;
    int v = (tid < nb) ? partials[tid] : 0;
    int lane = tid & 63, wid = tid >> 6;
    int x = v;
    for (int d = 1; d < 64; d <<= 1) { int tv = __shfl_up(x, d); if (lane >= d) x += tv; }
    __shared__ int wsum[16], woff[16];
    if (lane == 63) wsum[wid] = x;
    __syncthreads();
    if (tid < 16) {
        int s = 0;
        for (int i = 0; i < tid; i++) s += wsum[i];
        woff[tid] = s;
    }
    __syncthreads();
    int excl = x + woff[wid] - v;
    if (tid < nb) partials[tid] = excl;
}

__global__ void k_gfinal(int* __restrict__ a, const int* __restrict__ partials, int n) {
    int gid = blockIdx.x * 256 + threadIdx.x;
    int v = (gid < n) ? a[gid] : 0;
    int lane = threadIdx.x & 63, wid = threadIdx.x >> 6;
    int x = v;
    for (int d = 1; d < 64; d <<= 1) { int tv = __shfl_up(x, d); if (lane >= d) x += tv; }
    __shared__ int ws[4];
    if (lane == 63) ws[wid] = x;
    __syncthreads();
    int add = 0;
    for (int i = 0; i < wid; i++) add += ws[i];
    int excl = x - v + add + partials[blockIdx.x];
    if (gid < n) a[gid] = excl;
}

// ---------------------------------------------------------------- partition pass B
// rec.x = (row_in_bucket << 17) | src_col   (col < 2^17, rib < 512)
__global__ void __launch_bounds__(256) k_partB(const int* __restrict__ eu,
                                               const int* __restrict__ ee,
                                               const float* __restrict__ ew,
                                               const int* __restrict__ pos,
                                               int2* __restrict__ recs) {
    __shared__ int cur[NBUK];
    int t = threadIdx.x;
    for (int b = t; b < NBUK; b += 256) cur[b] = pos[b * NBLK + blockIdx.x];
    __syncthreads();
    int start = blockIdx.x * TILE, end = start + TILE;
    for (int i = start + t; i < end; i += 256) {
        int u = eu[i], e = ee[i];
        int wb = __float_as_int(ew[i]);
        int r1 = e;                         // entity-dest row, src = user u
        int p1 = atomicAdd(&cur[r1 >> SHIFT], 1);
        recs[p1] = make_int2(((r1 & (RPB - 1)) << 17) | u, wb);
        int r2 = NE + u;                    // user-dest row, src = entity e
        int p2 = atomicAdd(&cur[r2 >> SHIFT], 1);
        recs[p2] = make_int2(((r2 & (RPB - 1)) << 17) | e, wb);
    }
}

// ---------------------------------------------------------------- partition pass C
__global__ void __launch_bounds__(256) k_partC(const int* __restrict__ pos,
                                               const int2* __restrict__ recs,
                                               int2* __restrict__ edges,
                                               int* __restrict__ row_ptr) {
    int b = blockIdx.x;
    int t = threadIdx.x;
    __shared__ int hist[RPB];
    __shared__ int curs[RPB];
    __shared__ int wtot[4];
    int base = pos[b * NBLK];
    int nend = (b == NBUK - 1) ? TOT : pos[(b + 1) * NBLK];
    for (int r = t; r < RPB; r += 256) hist[r] = 0;
    __syncthreads();
    for (int i = base + t; i < nend; i += 256)
        atomicAdd(&hist[recs[i].x >> 17], 1);
    __syncthreads();
    int h0 = hist[2 * t], h1 = hist[2 * t + 1];
    int s = h0 + h1;
    int lane = t & 63, wid = t >> 6;
    int x = s;
    for (int d = 1; d < 64; d <<= 1) { int v = __shfl_up(x, d); if (lane >= d) x += v; }
    if (lane == 63) wtot[wid] = x;
    __syncthreads();
    int woff = 0;
    for (int i = 0; i < wid; i++) woff += wtot[i];
    int e0 = base + woff + x - s;          // absolute exclusive pos of row 2t
    curs[2 * t]     = e0;
    curs[2 * t + 1] = e0 + h0;
    int row0 = (b << SHIFT) + 2 * t;
    if (row0 < NROWS)     row_ptr[row0]     = e0;
    if (row0 + 1 < NROWS) row_ptr[row0 + 1] = e0 + h0;
    if (b == 0 && t == 0) row_ptr[NROWS]    = TOT;
    __syncthreads();
    for (int i = base + t; i < nend; i += 256) {
        int2 rc = recs[i];
        int p = atomicAdd(&curs[rc.x >> 17], 1);
        edges[p] = make_int2(rc.x & 0x1FFFF, rc.y);
    }
}

// ---------------------------------------------------------------- aggregation
// One wave per destination row. slot = lane>>4 picks edge-of-quad; l15 =
// lane&15 picks the feature quad (uint2 = 4 bf16). Edge records arrive via
// per-lane broadcast load of a contiguous 32B quad -- no selection ops.
__global__ void __launch_bounds__(256) k_agg(
        const int* __restrict__ row_ptr, const int2* __restrict__ edges,
        const ushort* __restrict__ uold, const ushort* __restrict__ eold,
        ushort* __restrict__ unew, ushort* __restrict__ enew,
        float* __restrict__ out) {
    int wid = threadIdx.x >> 6;
    int row = __builtin_amdgcn_readfirstlane(blockIdx.x * 4 + wid);
    if (row >= NROWS) return;
    int lane = threadIdx.x & 63;
    int slot = lane >> 4;        // edge within a quad
    int l15  = lane & 15;        // feature-quad index (feats 4*l15 .. 4*l15+3)

    const uint2* __restrict__ src;   // row stride = 16 uint2 (64 bf16)
    ushort* dst; float* op;
    if (row < NE) {                      // entity destination: gather user rows
        src = (const uint2*)uold;
        dst = enew + (size_t)row * DD;
        op  = out  + (size_t)row * DD;
    } else {                             // user destination: gather entity rows
        int r = row - NE;
        src = (const uint2*)eold;
        dst = unew + (size_t)r * DD;
        op  = out + EMB + (size_t)r * DD;
    }

    int s = row_ptr[row], e = row_ptr[row + 1];
    f32x2 a0 = {0.f, 0.f};   // feats 4*l15+0, +1
    f32x2 a1 = {0.f, 0.f};   // feats 4*l15+2, +3

    int j = s;
    for (; j + 16 <= e; j += 16) {       // 16 edges: 4 rec loads + 4 gathers in flight
        int2 rA = edges[j      + slot];
        int2 rB = edges[j + 4  + slot];
        int2 rC = edges[j + 8  + slot];
        int2 rD = edges[j + 12 + slot];
        uint2 gA = src[rA.x * 16 + l15];
        uint2 gB = src[rB.x * 16 + l15];
        uint2 gC = src[rC.x * 16 + l15];
        uint2 gD = src[rD.x * 16 + l15];
        f32x2 wA = {__int_as_float(rA.y), __int_as_float(rA.y)};
        f32x2 wB = {__int_as_float(rB.y), __int_as_float(rB.y)};
        f32x2 wC = {__int_as_float(rC.y), __int_as_float(rC.y)};
        f32x2 wD = {__int_as_float(rD.y), __int_as_float(rD.y)};
        f32x2 pA0 = {__uint_as_float(gA.x << 16), __uint_as_float(gA.x & 0xFFFF0000u)};
        f32x2 pA1 = {__uint_as_float(gA.y << 16), __uint_as_float(gA.y & 0xFFFF0000u)};
        f32x2 pB0 = {__uint_as_float(gB.x << 16), __uint_as_float(gB.x & 0xFFFF0000u)};
        f32x2 pB1 = {__uint_as_float(gB.y << 16), __uint_as_float(gB.y & 0xFFFF0000u)};
        f32x2 pC0 = {__uint_as_float(gC.x << 16), __uint_as_float(gC.x & 0xFFFF0000u)};
        f32x2 pC1 = {__uint_as_float(gC.y << 16), __uint_as_float(gC.y & 0xFFFF0000u)};
        f32x2 pD0 = {__uint_as_float(gD.x << 16), __uint_as_float(gD.x & 0xFFFF0000u)};
        f32x2 pD1 = {__uint_as_float(gD.y << 16), __uint_as_float(gD.y & 0xFFFF0000u)};
        a0 = pA0 * wA + a0;  a1 = pA1 * wA + a1;
        a0 = pB0 * wB + a0;  a1 = pB1 * wB + a1;
        a0 = pC0 * wC + a0;  a1 = pC1 * wC + a1;
        a0 = pD0 * wD + a0;  a1 = pD1 * wD + a1;
    }
    for (; j + 4 <= e; j += 4) {
        int2 r = edges[j + slot];
        uint2 g = src[r.x * 16 + l15];
        f32x2 w = {__int_as_float(r.y), __int_as_float(r.y)};
        f32x2 p0 = {__uint_as_float(g.x << 16), __uint_as_float(g.x & 0xFFFF0000u)};
        f32x2 p1 = {__uint_as_float(g.y << 16), __uint_as_float(g.y & 0xFFFF0000u)};
        a0 = p0 * w + a0;
        a1 = p1 * w + a1;
    }
    if (j < e) {                         // 1..3 remaining: predicated
        int idx = j + slot;
        bool valid = idx < e;
        int2 r = edges[valid ? idx : (e - 1)];
        uint2 g = src[r.x * 16 + l15];
        float wf = valid ? __int_as_float(r.y) : 0.f;
        f32x2 w = {wf, wf};
        f32x2 p0 = {__uint_as_float(g.x << 16), __uint_as_float(g.x & 0xFFFF0000u)};
        f32x2 p1 = {__uint_as_float(g.y << 16), __uint_as_float(g.y & 0xFFFF0000u)};
        a0 = p0 * w + a0;
        a1 = p1 * w + a1;
    }

    // combine the 4 edge slots (xor16: 0<->1, 2<->3; xor32: pairs)
    a0.x += __shfl_xor(a0.x, 16); a0.y += __shfl_xor(a0.y, 16);
    a1.x += __shfl_xor(a1.x, 16); a1.y += __shfl_xor(a1.y, 16);
    a0.x += __shfl_xor(a0.x, 32); a0.y += __shfl_xor(a0.y, 32);
    a1.x += __shfl_xor(a1.x, 32); a1.y += __shfl_xor(a1.y, 32);

    // L2 norm across the 16 feature-quads
    float sq = a0.x * a0.x;
    sq = fmaf(a0.y, a0.y, sq);
    sq = fmaf(a1.x, a1.x, sq);
    sq = fmaf(a1.y, a1.y, sq);
    for (int d = 8; d; d >>= 1) sq += __shfl_xor(sq, d);
    float inv = 1.0f / fmaxf(sqrtf(sq), 1e-12f);
    float n0 = a0.x * inv, n1 = a0.y * inv, n2 = a1.x * inv, n3 = a1.y * inv;

    if (slot == 0) {          // write bf16 next-hop row (packed, 8B/lane)
        uint2 p;
        p.x = (uint)f2bf(n0) | ((uint)f2bf(n1) << 16);
        p.y = (uint)f2bf(n2) | ((uint)f2bf(n3) << 16);
        ((uint2*)dst)[l15] = p;
    } else if (slot == 1) {   // f32 residual accumulate into d_out (16B/lane)
        float4* o4 = (float4*)op;
        float4 c = o4[l15];
        c.x += n0; c.y += n1; c.z += n2; c.w += n3;
        o4[l15] = c;
    }
}

// ---------------------------------------------------------------- launch
extern "C" void kernel_launch(void* const* d_in, const int* in_sizes, int n_in,
                              void* d_out, int out_size, void* d_ws, size_t ws_size,
                              hipStream_t stream) {
    const float* uemb = (const float*)d_in[0];
    const float* eemb = (const float*)d_in[1];
    const int*   eu   = (const int*)d_in[2];
    const int*   ee   = (const int*)d_in[3];
    const float* ew   = (const float*)d_in[4];
    float* out = (float*)d_out;

    // workspace carve-up (~156 MB)
    char* ws = (char*)d_ws;
    size_t off = 0;
    ushort* ucur0 = (ushort*)(ws + off); off += (size_t)EMB * 2;   // 12.8 MB each
    ushort* ecur0 = (ushort*)(ws + off); off += (size_t)EMB * 2;
    ushort* ucur1 = (ushort*)(ws + off); off += (size_t)EMB * 2;
    ushort* ecur1 = (ushort*)(ws + off); off += (size_t)EMB * 2;
    int2*  recs    = (int2*)(ws + off);  off += (size_t)TOT * 8;   // 51.2 MB
    int2*  edges   = (int2*)(ws + off);  off += (size_t)TOT * 8;   // 51.2 MB
    int*   row_ptr = (int*)(ws + off);   off += (size_t)(NROWS + 1) * 4;
    int*   pos     = (int*)(ws + off);   off += (size_t)NBUK * NBLK * 4;
    int*   partials= (int*)(ws + off);   off += 1024 * 4;

    // 1. convert embeddings to bf16 tables, init output residuals
    k_init<<<2048, 256, 0, stream>>>((const float4*)uemb, (const float4*)eemb,
                                     (ushort4*)ucur0, (ushort4*)ecur0, (float4*)out);

    // 2. per-(block,bucket) histogram
    k_bhist<<<NBLK, 256, 0, stream>>>(eu, ee, pos);

    // 3. exclusive scan of NBUK*NBLK counters (bucket-major)
    const int NSCAN = NBUK * NBLK;               // 200192
    const int NB = (NSCAN + 255) / 256;          // 782
    k_gsum<<<NB, 256, 0, stream>>>(pos, partials, NSCAN);
    k_gtop<<<1, 1024, 0, stream>>>(partials, NB);
    k_gfinal<<<NB, 256, 0, stream>>>(pos, partials, NSCAN);

    // 4. partition into bucket-major staging (coalesced block-owned runs)
    k_partB<<<NBLK, 256, 0, stream>>>(eu, ee, ew, pos, recs);

    // 5. per-bucket scatter to final CSR order + emit row_ptr
    k_partC<<<NBUK, 256, 0, stream>>>(pos, recs, edges, row_ptr);

    // 6. three fused aggregation hops
    const int AB = (NROWS + 3) / 4;      // 50000 blocks, 4 waves = 4 rows each
    k_agg<<<AB, 256, 0, stream>>>(row_ptr, edges, ucur0, ecur0, ucur1, ecur1, out);
    k_agg<<<AB, 256, 0, stream>>>(row_ptr, edges, ucur1, ecur1, ucur0, ecur0, out);
    k_agg<<<AB, 256, 0, stream>>>(row_ptr, edges, ucur0, ecur0, ucur1, ecur1, out);
}